// Round 10
// baseline (114.173 us; speedup 1.0000x reference)
//
#include <hip/hip_runtime.h>
#include <math.h>

constexpr int kB = 16, kC = 128, kHW = 4096, kL = 512, kND = 256, kG = 32;
constexpr float kEps = 1e-6f;
constexpr float kScale = 0.08838834764831845f;  // 128^-0.5

typedef short sv8 __attribute__((ext_vector_type(8)));
typedef int   iv4 __attribute__((ext_vector_type(4)));
typedef float f32x16 __attribute__((ext_vector_type(16)));

static __device__ __forceinline__ unsigned short f2bf(float f) {
    unsigned int u = __builtin_bit_cast(unsigned int, f);
    u += 0x7fffu + ((u >> 16) & 1u);
    return (unsigned short)(u >> 16);
}
static __device__ __forceinline__ float bf2f(unsigned short s) {
    unsigned int u = ((unsigned int)s) << 16;
    return __builtin_bit_cast(float, u);
}
static __device__ __forceinline__ unsigned int pack2(float a, float b) {
    return (unsigned int)f2bf(a) | ((unsigned int)f2bf(b) << 16);
}

// Direct global->LDS async copy, 16 B/lane. LDS dest is wave-uniform base +
// lane*16 (linear); swizzle is applied by permuting the per-lane SOURCE.
#define GLOAD_LDS16(gp, lp)                                                     \
    __builtin_amdgcn_global_load_lds(                                           \
        (const __attribute__((address_space(1))) void*)(gp),                    \
        (__attribute__((address_space(3))) void*)(lp), 16, 0, 0)

// ---------------- Kernel 1: GroupNorm statistics ----------------
__global__ __launch_bounds__(256) void gn_stats_k(const float* __restrict__ x,
                                                  float* __restrict__ stats) {
    int bg = blockIdx.x;
    const float4* p4 = (const float4*)(x + (size_t)bg * 4 * kHW);
    int tid = threadIdx.x;
    float s = 0.f, ss = 0.f;
    for (int i = tid; i < 4096; i += 256) {
        float4 v = p4[i];
        s  += (v.x + v.y) + (v.z + v.w);
        ss += (v.x * v.x + v.y * v.y) + (v.z * v.z + v.w * v.w);
    }
#pragma unroll
    for (int off = 1; off < 64; off <<= 1) {
        s  += __shfl_xor(s, off, 64);
        ss += __shfl_xor(ss, off, 64);
    }
    __shared__ float red[8];
    int wid = tid >> 6;
    if ((tid & 63) == 0) { red[wid] = s; red[wid + 4] = ss; }
    __syncthreads();
    if (tid == 0) {
        float S  = (red[0] + red[1]) + (red[2] + red[3]);
        float SS = (red[4] + red[5]) + (red[6] + red[7]);
        float mean = S * (1.f / 16384.f);
        float var  = SS * (1.f / 16384.f) - mean * mean;
        stats[bg * 2]     = mean;
        stats[bg * 2 + 1] = rsqrtf(var + kEps);
    }
}

// ---------------- Kernel 1b: proj_w -> bf16 ----------------
__global__ __launch_bounds__(256) void prep_k(const float* __restrict__ w,
                                              unsigned short* __restrict__ wb) {
    int i = (blockIdx.x * 256 + threadIdx.x) * 4;
    float4 v = *(const float4*)(w + i);
    wb[i + 0] = f2bf(v.x); wb[i + 1] = f2bf(v.y);
    wb[i + 2] = f2bf(v.z); wb[i + 3] = f2bf(v.w);
}

// ---------------- Kernel 2: kv = silu(nd) @ nd_w^T + nd_b (bf16 + bf16^T) ----
__global__ __launch_bounds__(256) void kv_k(const float* __restrict__ nd,
                                            const float* __restrict__ nd_w,
                                            const float* __restrict__ nd_b,
                                            unsigned short* __restrict__ kv_bf,
                                            unsigned short* __restrict__ kvT_bf) {
    __shared__ float s_lds[8][256];
    __shared__ float w_lds[128][68];
    __shared__ float t_lds[8][129];
    int b = blockIdx.y;
    int l0 = blockIdx.x * 8;
    int tid = threadIdx.x;
    const float4* ndp = (const float4*)(nd + ((size_t)b * kL + l0) * kND);
#pragma unroll
    for (int r = 0; r < 2; r++) {
        int idx = tid + r * 256;
        int row = idx >> 6;
        int c4 = idx & 63;
        float4 v = ndp[row * 64 + c4];
        v.x = v.x / (1.f + __expf(-v.x));
        v.y = v.y / (1.f + __expf(-v.y));
        v.z = v.z / (1.f + __expf(-v.z));
        v.w = v.w / (1.f + __expf(-v.w));
        *(float4*)&s_lds[row][c4 * 4] = v;
    }
    float acc[4] = {0.f, 0.f, 0.f, 0.f};
    int lr = tid >> 5;
    int oq = tid & 31;
    for (int d0 = 0; d0 < kND; d0 += 64) {
        __syncthreads();
#pragma unroll
        for (int r = 0; r < 8; r++) {
            int idx = tid + r * 256;
            int row = idx >> 4;
            int c4 = idx & 15;
            float4 v = ((const float4*)(nd_w + (size_t)row * kND + d0))[c4];
            *(float4*)&w_lds[row][c4 * 4] = v;
        }
        __syncthreads();
        for (int dd = 0; dd < 64; dd += 4) {
            float4 sv = *(const float4*)&s_lds[lr][d0 + dd];
#pragma unroll
            for (int j = 0; j < 4; j++) {
                float4 wv = *(const float4*)&w_lds[oq + 32 * j][dd];
                acc[j] += sv.x * wv.x + sv.y * wv.y + sv.z * wv.z + sv.w * wv.w;
            }
        }
    }
#pragma unroll
    for (int j = 0; j < 4; j++) {
        int o = oq + 32 * j;
        float vout = acc[j] + nd_b[o];
        kv_bf[((size_t)b * kL + l0 + lr) * kC + o] = f2bf(vout);
        t_lds[lr][o] = vout;
    }
    __syncthreads();
    {
        int o = tid >> 1, lh = (tid & 1) * 4;
        unsigned long long pk = 0;
#pragma unroll
        for (int i = 0; i < 4; i++)
            pk |= (unsigned long long)f2bf(t_lds[lh + i][o]) << (16 * i);
        *(unsigned long long*)(kvT_bf + ((size_t)b * kC + o) * kL + l0 + lh) = pk;
    }
}

// ---------------- Kernel 3: q = (GN(x))^T @ q_w^T + q_b  (bf16 MFMA) -------
__global__ __launch_bounds__(256) void qproj_k(const float* __restrict__ x,
                                               const float* __restrict__ stats,
                                               const float* __restrict__ gamma,
                                               const float* __restrict__ beta,
                                               const float* __restrict__ q_w,
                                               const float* __restrict__ q_b,
                                               unsigned short* __restrict__ q_bf) {
    __shared__ __align__(16) unsigned short smem[17408];  // [128][136] bf16
    __shared__ float gab[256];                            // ga[128], be[128]
    const int b = blockIdx.y;
    const int n0 = blockIdx.x * 128;
    const int tid = threadIdx.x;
    const int wave = tid >> 6, lane = tid & 63;
    const int lrow = lane & 31, hi = lane >> 5;

    if (tid < 128) {
        float mean = stats[(b * kG + (tid >> 2)) * 2];
        float rstd = stats[(b * kG + (tid >> 2)) * 2 + 1];
        float ga = gamma[tid] * rstd;
        gab[tid] = ga;
        gab[128 + tid] = beta[tid] - mean * ga;
    }
    // stage q_w as bf16 [o][c], padded stride 136
#pragma unroll
    for (int r = 0; r < 16; r++) {
        int idx = tid + r * 256;            // 4096 float4 = 128x32
        int row = idx >> 5, c4 = idx & 31;
        float4 v = ((const float4*)q_w)[idx];
        unsigned int lo = (unsigned int)f2bf(v.x) | ((unsigned int)f2bf(v.y) << 16);
        unsigned int h2 = (unsigned int)f2bf(v.z) | ((unsigned int)f2bf(v.w) << 16);
        *(uint2*)&smem[row * 136 + c4 * 4] = make_uint2(lo, h2);
    }
    __syncthreads();

    // A fragments: hn[n][c] with GN fused, straight from global
    sv8 qa[8];
    {
        const float* xp = x + (size_t)b * kC * kHW + n0 + wave * 32 + lrow;
#pragma unroll
        for (int kc = 0; kc < 8; kc++) {
            int cb = kc * 16 + hi * 8;
            float4 g0 = *(const float4*)&gab[cb];
            float4 g1 = *(const float4*)&gab[cb + 4];
            float4 e0 = *(const float4*)&gab[128 + cb];
            float4 e1 = *(const float4*)&gab[128 + cb + 4];
            sv8 a;
            a[0] = (short)f2bf(xp[(size_t)(cb + 0) * kHW] * g0.x + e0.x);
            a[1] = (short)f2bf(xp[(size_t)(cb + 1) * kHW] * g0.y + e0.y);
            a[2] = (short)f2bf(xp[(size_t)(cb + 2) * kHW] * g0.z + e0.z);
            a[3] = (short)f2bf(xp[(size_t)(cb + 3) * kHW] * g0.w + e0.w);
            a[4] = (short)f2bf(xp[(size_t)(cb + 4) * kHW] * g1.x + e1.x);
            a[5] = (short)f2bf(xp[(size_t)(cb + 5) * kHW] * g1.y + e1.y);
            a[6] = (short)f2bf(xp[(size_t)(cb + 6) * kHW] * g1.z + e1.z);
            a[7] = (short)f2bf(xp[(size_t)(cb + 7) * kHW] * g1.w + e1.w);
            qa[kc] = a;
        }
    }

    f32x16 dacc[4];
#pragma unroll
    for (int ot = 0; ot < 4; ot++)
#pragma unroll
        for (int r = 0; r < 16; r++) dacc[ot][r] = 0.f;
#pragma unroll
    for (int ot = 0; ot < 4; ot++) {
        const unsigned short* brow = smem + (ot * 32 + lrow) * 136 + hi * 8;
#pragma unroll
        for (int kc = 0; kc < 8; kc++)
            dacc[ot] = __builtin_amdgcn_mfma_f32_32x32x16_bf16(
                           qa[kc], *(const sv8*)(brow + kc * 16), dacc[ot], 0, 0, 0);
    }
    __syncthreads();   // all B-reads done; reuse smem as q[n][o] transpose

#pragma unroll
    for (int ot = 0; ot < 4; ot++) {
        int o = ot * 32 + lrow;
        float qb = q_b[o];
#pragma unroll
        for (int r = 0; r < 16; r++) {
            int n_loc = wave * 32 + (r & 3) + 8 * (r >> 2) + 4 * hi;
            smem[n_loc * 136 + o] = f2bf((dacc[ot][r] + qb) * kScale);
        }
    }
    __syncthreads();
#pragma unroll
    for (int r = 0; r < 8; r++) {
        int idx = tid + r * 256;            // 2048 uint4 = 128 rows x 16
        int n = idx >> 4, ch = idx & 15;
        *(uint4*)(q_bf + ((size_t)b * kHW + n0 + n) * kC + ch * 8) =
            *(const uint4*)&smem[n * 136 + ch * 8];
    }
}

// ---------------- Kernel 4: MFMA attention + proj + residual ----------------
// Split-KV: 512 threads / 8 waves; waves 0-3 handle l in [0,256), waves 4-7
// l in [256,512), SAME 128 Q-rows. 4096 total waves -> 16 waves/CU (4/SIMD,
// needs <=128 regs -> launch_bounds(512,4)). Max-free softmax => partials
// combine by plain sums through LDS. KVBLK=32 per half, dbuf,
// global_load_lds staging with pre-swizzled sources.
__global__ __launch_bounds__(512, 4) void attn_k(
    const unsigned short* __restrict__ qb,    // [B][HW][C] bf16, pre-scaled
    const unsigned short* __restrict__ kvb,   // [B][L][C] bf16
    const unsigned short* __restrict__ kvtb,  // [B][C][L] bf16
    const unsigned short* __restrict__ pwb,   // [C][C] bf16 (o-major)
    const float* __restrict__ proj_b,
    const float* __restrict__ x,
    float* __restrict__ out)
{
    __shared__ __align__(16) char smem[67072];
    // half h at smem + h*32768:
    //   [0,16K):  kvA dbuf ([32 l][128 c] bf16, ch16 ^= (l&15)), 8K each
    //   [16K,32K): kvT dbuf ([128 c][32 l] bf16, ch4 ^= ((c>>1)&3)), 8K each
    // [65536,66560): rsp 8 waves x 32 f32 (partial rowsums)
    // [66560,67072): ginv 4 waves x 32 f32 (1/total)
    // post-loop: combine area f32[16384] at 0; then o_lds ushort[128][136] at 0

    const int flat = blockIdx.y * gridDim.x + blockIdx.x;   // 0..511
    const int b  = ((flat & 7) << 1) | ((flat >> 3) & 1);   // XCD-clustered
    const int n0 = (flat >> 4) * 128;
    const int tid = threadIdx.x;
    const int wave = tid >> 6;        // 0..7
    const int half = wave >> 2;       // l-half
    const int w4 = wave & 3;          // wave within half
    const int lane = tid & 63;
    const int lrow = lane & 31;
    const int hi = lane >> 5;
    const int swzA = (lrow & 15) << 4;
    const int swzT = ((lrow >> 1) & 3) << 4;
    char* hbase = smem + half * 32768;

    // Q fragments (B-operand of the swapped QK^T); both halves same rows
    sv8 qa[8];
    {
        const unsigned short* qrow =
            qb + ((size_t)b * kHW + n0 + w4 * 32 + lrow) * kC + hi * 8;
#pragma unroll
        for (int kc = 0; kc < 8; kc++)
            qa[kc] = *(const sv8*)(qrow + kc * 16);
    }

    f32x16 oacc[4];
#pragma unroll
    for (int ct = 0; ct < 4; ct++)
#pragma unroll
        for (int r = 0; r < 16; r++) oacc[ct][r] = 0.f;
    float rsumv = 0.f;

    const unsigned short* kvB  = kvb  + (size_t)b * kL * kC;
    const unsigned short* kvtB = kvtb + (size_t)b * kC * kL;

    // staging: 4 global_load_lds per thread per 32-l tile (own half)
#define STAGE_TILE(tt) do {                                                     \
        int l0s = half * 256 + ((tt) << 5);                                     \
        char* dA = hbase + (((tt) & 1) * 8192);                                 \
        char* dT = hbase + 16384 + (((tt) & 1) * 8192);                         \
        _Pragma("unroll")                                                       \
        for (int i = 0; i < 2; i++) {                                           \
            int l = i * 16 + w4 * 4 + (lane >> 4);                              \
            int ch = lane & 15;                                                 \
            const unsigned short* gs =                                          \
                kvB + (size_t)(l0s + l) * kC + ((ch ^ (l & 15)) * 8);           \
            GLOAD_LDS16(gs, dA + (i * 256 + w4 * 64) * 16);                     \
        }                                                                       \
        _Pragma("unroll")                                                       \
        for (int i = 0; i < 2; i++) {                                           \
            int c = i * 64 + w4 * 16 + (lane >> 2);                             \
            int ch = lane & 3;                                                  \
            const unsigned short* gs =                                          \
                kvtB + (size_t)c * kL + l0s + ((ch ^ ((c >> 1) & 3)) * 8);      \
            GLOAD_LDS16(gs, dT + (i * 256 + w4 * 64) * 16);                     \
        }                                                                       \
    } while (0)

    STAGE_TILE(0);
    __syncthreads();           // barrier drains vmcnt -> tile 0 visible

    for (int t = 0; t < 8; t++) {
        const char* bufA = hbase + (t & 1) * 8192;
        const char* bufT = hbase + 16384 + (t & 1) * 8192;
        if (t < 7) STAGE_TILE(t + 1);    // in flight across the compute phase

        // ---- swapped QK^T: S[l][n] = mfma(A=kv, B=q); exp in registers ----
        f32x16 s;
#pragma unroll
        for (int r = 0; r < 16; r++) s[r] = 0.f;
        {
            const char* arow = bufA + lrow * 256;
            __builtin_amdgcn_s_setprio(1);
#pragma unroll
            for (int kc = 0; kc < 8; kc++)
                s = __builtin_amdgcn_mfma_f32_32x32x16_bf16(
                        *(const sv8*)(arow + ((kc * 32 + hi * 16) ^ swzA)),
                        qa[kc], s, 0, 0, 0);
            __builtin_amdgcn_s_setprio(0);
        }
        // exp fused with pack (no p[16] array -> lower reg pressure)
        unsigned int pk[4], pk2[4];
#pragma unroll
        for (int g = 0; g < 4; g++) {
            float e0 = __expf(s[4 * g + 0]);
            float e1 = __expf(s[4 * g + 1]);
            float e2 = __expf(s[4 * g + 2]);
            float e3 = __expf(s[4 * g + 3]);
            rsumv += (e0 + e1) + (e2 + e3);
            pk[g]  = pack2(e0, e1);
            pk2[g] = pack2(e2, e3);
        }
        // ---- assemble PV A-fragments: lane n holds P[n][l], l=kk*16+hi*8+j.
        sv8 pv[2];
#pragma unroll
        for (int kk = 0; kk < 2; kk++) {
            unsigned int a_lo = pk[kk * 2],  a_hi = pk[kk * 2 + 1];
            unsigned int b_lo = pk2[kk * 2], b_hi = pk2[kk * 2 + 1];
            unsigned int own_a = hi ? a_hi : a_lo;
            unsigned int own_b = hi ? b_hi : b_lo;
            unsigned int rcv_a = (unsigned int)__shfl_xor((int)(hi ? a_lo : a_hi), 32, 64);
            unsigned int rcv_b = (unsigned int)__shfl_xor((int)(hi ? b_lo : b_hi), 32, 64);
            iv4 w;
            w[0] = (int)(hi ? rcv_a : own_a);
            w[1] = (int)(hi ? rcv_b : own_b);
            w[2] = (int)(hi ? own_a : rcv_a);
            w[3] = (int)(hi ? own_b : rcv_b);
            pv[kk] = __builtin_bit_cast(sv8, w);
        }
        // ---- PV: O[n][c] += P[n][l] * kv[l][c]; B from swizzled kvT ----
        __builtin_amdgcn_s_setprio(1);
#pragma unroll
        for (int ct = 0; ct < 4; ct++) {
            const char* rowp = bufT + (ct * 32 + lrow) * 64;
#pragma unroll
            for (int kk = 0; kk < 2; kk++)
                oacc[ct] = __builtin_amdgcn_mfma_f32_32x32x16_bf16(
                               pv[kk],
                               *(const sv8*)(rowp + ((kk * 32 + hi * 16) ^ swzT)),
                               oacc[ct], 0, 0, 0);
        }
        __builtin_amdgcn_s_setprio(0);

        __syncthreads();   // drains vmcnt (t+1 landed) + guards dbuf swap
    }

    // ---- combine the two l-halves (plain sums; max-free softmax) ----
    float* cx  = (float*)smem;                   // f32[16384], reuses kv area
    float* rsp = (float*)(smem + 65536);         // [8][32]
    float* giv = (float*)(smem + 66560);         // [4][32]
    {
        float total_half = rsumv + __shfl_xor(rsumv, 32, 64);
        rsp[wave * 32 + lrow] = total_half;      // hi lanes dup-write same val
    }
    if (half) {
#pragma unroll
        for (int ct = 0; ct < 4; ct++)
#pragma unroll
            for (int r = 0; r < 16; r++)
                cx[w4 * 4096 + ct * 1024 + r * 64 + lane] = oacc[ct][r];
    }
    __syncthreads();
    if (!half) {
#pragma unroll
        for (int ct = 0; ct < 4; ct++)
#pragma unroll
            for (int r = 0; r < 16; r++)
                oacc[ct][r] += cx[w4 * 4096 + ct * 1024 + r * 64 + lane];
        float grand = rsp[wave * 32 + lrow] + rsp[(wave + 4) * 32 + lrow];
        giv[wave * 32 + lrow] = 1.f / grand;
    }
    __syncthreads();   // combine reads done; o_lds may overwrite

    unsigned short* o_lds = (unsigned short*)smem;   // [128][136]
    if (!half) {
        float rinv[16];
#pragma unroll
        for (int r = 0; r < 16; r++)
            rinv[r] = giv[w4 * 32 + (r & 3) + 8 * (r >> 2) + 4 * hi];
        // normalized O -> o_lds bf16 [128 n][136 c] (own rows only)
#pragma unroll
        for (int ct = 0; ct < 4; ct++)
#pragma unroll
            for (int r = 0; r < 16; r++) {
                int n = w4 * 32 + (r & 3) + 8 * (r >> 2) + 4 * hi;
                o_lds[n * 136 + ct * 32 + lrow] = f2bf(oacc[ct][r] * rinv[r]);
            }
        // proj: D[n][o] = O[n][c] * pw[o][c]
        sv8 oa[8];
        const unsigned short* orow = o_lds + (w4 * 32 + lrow) * 136 + hi * 8;
#pragma unroll
        for (int kc = 0; kc < 8; kc++) oa[kc] = *(const sv8*)(orow + kc * 16);
        f32x16 dacc[4];
#pragma unroll
        for (int ot = 0; ot < 4; ot++)
#pragma unroll
            for (int r = 0; r < 16; r++) dacc[ot][r] = 0.f;
#pragma unroll
        for (int ot = 0; ot < 4; ot++) {
            const unsigned short* brow = pwb + (ot * 32 + lrow) * kC + hi * 8;
#pragma unroll
            for (int kc = 0; kc < 8; kc++)
                dacc[ot] = __builtin_amdgcn_mfma_f32_32x32x16_bf16(
                               oa[kc], *(const sv8*)(brow + kc * 16), dacc[ot], 0, 0, 0);
        }
        // D -> o_lds bf16 [128 n][136 o] (own rows; reads already in regs)
#pragma unroll
        for (int ot = 0; ot < 4; ot++)
#pragma unroll
            for (int r = 0; r < 16; r++) {
                int n = w4 * 32 + (r & 3) + 8 * (r >> 2) + 4 * hi;
                o_lds[n * 136 + ot * 32 + lrow] = f2bf(dacc[ot][r]);
            }
    }
    __syncthreads();
    // epilogue: out[b][o][n0+n] = D[n][o] + proj_b[o] + x  (all 512 threads)
#pragma unroll 4
    for (int it = 0; it < 32; it++) {
        int idx = it * 512 + tid;
        int o = idx >> 7, n = idx & 127;
        size_t gi = ((size_t)b * kC + o) * kHW + n0 + n;
        out[gi] = bf2f(o_lds[n * 136 + o]) + proj_b[o] + x[gi];
    }
#undef STAGE_TILE
}

extern "C" void kernel_launch(void* const* d_in, const int* in_sizes, int n_in,
                              void* d_out, int out_size, void* d_ws, size_t ws_size,
                              hipStream_t stream) {
    const float* x      = (const float*)d_in[0];
    const float* nd     = (const float*)d_in[1];
    const float* gamma  = (const float*)d_in[2];
    const float* beta   = (const float*)d_in[3];
    const float* q_w    = (const float*)d_in[4];
    const float* q_b    = (const float*)d_in[5];
    const float* nd_w   = (const float*)d_in[6];
    const float* nd_b   = (const float*)d_in[7];
    const float* proj_w = (const float*)d_in[8];
    const float* proj_b = (const float*)d_in[9];
    float* out = (float*)d_out;

    float* stats          = (float*)d_ws;                  // 1024 f32
    unsigned short* pwb   = (unsigned short*)(stats + 1024);       // 16384
    unsigned short* kv_bf = pwb + 16384;                   // 1,048,576
    unsigned short* kvT_bf = kv_bf + (size_t)kB * kL * kC; // 1,048,576
    unsigned short* q_bf  = kvT_bf + (size_t)kB * kL * kC; // 8,388,608

    gn_stats_k<<<dim3(kB * kG), dim3(256), 0, stream>>>(x, stats);
    prep_k<<<dim3(16), dim3(256), 0, stream>>>(proj_w, pwb);
    kv_k<<<dim3(kL / 8, kB), dim3(256), 0, stream>>>(nd, nd_w, nd_b, kv_bf, kvT_bf);
    qproj_k<<<dim3(kHW / 128, kB), dim3(256), 0, stream>>>(x, stats, gamma, beta, q_w, q_b, q_bf);
    attn_k<<<dim3(kHW / 128, kB), dim3(512), 0, stream>>>(q_bf, kv_bf, kvT_bf, pwb,
                                                          proj_b, x, out);
}

// Round 11
// 81.156 us; speedup vs baseline: 1.4068x; 1.4068x over previous
//
#include <hip/hip_runtime.h>
#include <math.h>

constexpr int kB = 16, kC = 128, kHW = 4096, kL = 512, kND = 256, kG = 32;
constexpr float kEps = 1e-6f;
constexpr float kScale = 0.08838834764831845f;  // 128^-0.5

typedef short sv8 __attribute__((ext_vector_type(8)));
typedef int   iv4 __attribute__((ext_vector_type(4)));
typedef float f32x16 __attribute__((ext_vector_type(16)));

static __device__ __forceinline__ unsigned short f2bf(float f) {
    unsigned int u = __builtin_bit_cast(unsigned int, f);
    u += 0x7fffu + ((u >> 16) & 1u);
    return (unsigned short)(u >> 16);
}
static __device__ __forceinline__ float bf2f(unsigned short s) {
    unsigned int u = ((unsigned int)s) << 16;
    return __builtin_bit_cast(float, u);
}
static __device__ __forceinline__ unsigned int pack2(float a, float b) {
    return (unsigned int)f2bf(a) | ((unsigned int)f2bf(b) << 16);
}

// Direct global->LDS async copy, 16 B/lane. LDS dest is wave-uniform base +
// lane*16 (linear); swizzle is applied by permuting the per-lane SOURCE.
#define GLOAD_LDS16(gp, lp)                                                     \
    __builtin_amdgcn_global_load_lds(                                           \
        (const __attribute__((address_space(1))) void*)(gp),                    \
        (__attribute__((address_space(3))) void*)(lp), 16, 0, 0)

// =========== Kernel 1: gn_stats + kv (+bf16/bf16^T) + proj_w->bf16 ==========
// One launch, block-range dispatch: [0,512) gn_stats, [512,1536) kv, rest prep.
__global__ __launch_bounds__(256) void prep_all_k(
    const float* __restrict__ x, const float* __restrict__ nd,
    const float* __restrict__ nd_w, const float* __restrict__ nd_b,
    const float* __restrict__ proj_w,
    float* __restrict__ stats, unsigned short* __restrict__ kv_bf,
    unsigned short* __restrict__ kvT_bf, unsigned short* __restrict__ pwb)
{
    __shared__ float s_lds[8][256];
    __shared__ float w_lds[128][68];
    __shared__ float t_lds[8][129];
    __shared__ float red8[8];
    const int bid = blockIdx.x;
    const int tid = threadIdx.x;

    if (bid < 512) {
        // ---------------- GroupNorm statistics ----------------
        const float4* p4 = (const float4*)(x + (size_t)bid * 4 * kHW);
        float s = 0.f, ss = 0.f;
        for (int i = tid; i < 4096; i += 256) {
            float4 v = p4[i];
            s  += (v.x + v.y) + (v.z + v.w);
            ss += (v.x * v.x + v.y * v.y) + (v.z * v.z + v.w * v.w);
        }
#pragma unroll
        for (int off = 1; off < 64; off <<= 1) {
            s  += __shfl_xor(s, off, 64);
            ss += __shfl_xor(ss, off, 64);
        }
        int wid = tid >> 6;
        if ((tid & 63) == 0) { red8[wid] = s; red8[wid + 4] = ss; }
        __syncthreads();
        if (tid == 0) {
            float S  = (red8[0] + red8[1]) + (red8[2] + red8[3]);
            float SS = (red8[4] + red8[5]) + (red8[6] + red8[7]);
            float mean = S * (1.f / 16384.f);
            float var  = SS * (1.f / 16384.f) - mean * mean;
            stats[bid * 2]     = mean;
            stats[bid * 2 + 1] = rsqrtf(var + kEps);
        }
        return;
    }
    if (bid >= 1536) {
        // ---------------- proj_w -> bf16 ----------------
        int i = ((bid - 1536) * 256 + tid) * 4;
        float4 v = *(const float4*)(proj_w + i);
        pwb[i + 0] = f2bf(v.x); pwb[i + 1] = f2bf(v.y);
        pwb[i + 2] = f2bf(v.z); pwb[i + 3] = f2bf(v.w);
        return;
    }
    // ---------------- kv = silu(nd) @ nd_w^T + nd_b ----------------
    {
        int idx0 = bid - 512;
        int b = idx0 >> 6;
        int l0 = (idx0 & 63) * 8;
        const float4* ndp = (const float4*)(nd + ((size_t)b * kL + l0) * kND);
#pragma unroll
        for (int r = 0; r < 2; r++) {
            int idx = tid + r * 256;
            int row = idx >> 6;
            int c4 = idx & 63;
            float4 v = ndp[row * 64 + c4];
            v.x = v.x / (1.f + __expf(-v.x));
            v.y = v.y / (1.f + __expf(-v.y));
            v.z = v.z / (1.f + __expf(-v.z));
            v.w = v.w / (1.f + __expf(-v.w));
            *(float4*)&s_lds[row][c4 * 4] = v;
        }
        float acc[4] = {0.f, 0.f, 0.f, 0.f};
        int lr = tid >> 5;
        int oq = tid & 31;
        for (int d0 = 0; d0 < kND; d0 += 64) {
            __syncthreads();
#pragma unroll
            for (int r = 0; r < 8; r++) {
                int idx = tid + r * 256;
                int row = idx >> 4;
                int c4 = idx & 15;
                float4 v = ((const float4*)(nd_w + (size_t)row * kND + d0))[c4];
                *(float4*)&w_lds[row][c4 * 4] = v;
            }
            __syncthreads();
            for (int dd = 0; dd < 64; dd += 4) {
                float4 sv = *(const float4*)&s_lds[lr][d0 + dd];
#pragma unroll
                for (int j = 0; j < 4; j++) {
                    float4 wv = *(const float4*)&w_lds[oq + 32 * j][dd];
                    acc[j] += sv.x * wv.x + sv.y * wv.y + sv.z * wv.z + sv.w * wv.w;
                }
            }
        }
#pragma unroll
        for (int j = 0; j < 4; j++) {
            int o = oq + 32 * j;
            float vout = acc[j] + nd_b[o];
            kv_bf[((size_t)b * kL + l0 + lr) * kC + o] = f2bf(vout);
            t_lds[lr][o] = vout;
        }
        __syncthreads();
        int o = tid >> 1, lh = (tid & 1) * 4;
        unsigned long long pk = 0;
#pragma unroll
        for (int i = 0; i < 4; i++)
            pk |= (unsigned long long)f2bf(t_lds[lh + i][o]) << (16 * i);
        *(unsigned long long*)(kvT_bf + ((size_t)b * kC + o) * kL + l0 + lh) = pk;
    }
}

// ========== Kernel 2: fused GN+qproj prologue + attention + proj ============
// Block: 128 Q-rows x 1 batch, 4 waves x 32 rows, 256 threads, 2 blocks/CU.
// Prologue computes q in-block (GN fused from x, q_w staged bf16 in LDS,
// swapped-operand MFMA -> lane-local q, pack2+shfl into qa fragments).
// Main loop = round-9 core: KVBLK=32, swapped QK^T (P in registers),
// global_load_lds staging with pre-swizzled sources, dbuf, 1 barrier/tile.
__global__ __launch_bounds__(256, 2) void attn_k(
    const float* __restrict__ x,
    const float* __restrict__ stats,
    const float* __restrict__ gamma,
    const float* __restrict__ beta,
    const float* __restrict__ q_w,
    const float* __restrict__ q_b,
    const unsigned short* __restrict__ kvb,   // [B][L][C] bf16
    const unsigned short* __restrict__ kvtb,  // [B][C][L] bf16
    const unsigned short* __restrict__ pwb,   // [C][C] bf16 (o-major)
    const float* __restrict__ proj_b,
    float* __restrict__ out)
{
    __shared__ __align__(16) char smem[36864];
    // [0,34816):      prologue qw_lds [128][136] bf16
    //                 main loop: kvA dbuf [0,16384) ([32 l][128 c], ch16^=(l&15))
    //                            kvT dbuf [16384,32768) ([128 c][32 l], ch4^=((c>>1)&3))
    //                 epilogue: o_lds ushort [128][136]
    // [34816,36352):  gtab = ga[128] | be[128] | qb[128] f32
    // [36352,36864):  rs 4 waves x 32 f32 (1/rowsum)

    const int flat = blockIdx.y * gridDim.x + blockIdx.x;   // 0..511
    const int b  = ((flat & 7) << 1) | ((flat >> 3) & 1);   // XCD-clustered
    const int n0 = (flat >> 4) * 128;
    const int tid = threadIdx.x;
    const int wave = tid >> 6;
    const int lane = tid & 63;
    const int lrow = lane & 31;
    const int hi = lane >> 5;
    const int swzA = (lrow & 15) << 4;
    const int swzT = ((lrow >> 1) & 3) << 4;

    unsigned short* qw = (unsigned short*)smem;      // [128][136]
    float* gtab = (float*)(smem + 34816);            // ga | be | qb

    // ---- prologue part 1: GN tables + q_w staged bf16 ----
    if (tid < 128) {
        float mean = stats[(b * kG + (tid >> 2)) * 2];
        float rstd = stats[(b * kG + (tid >> 2)) * 2 + 1];
        float ga = gamma[tid] * rstd;
        gtab[tid] = ga;
        gtab[128 + tid] = beta[tid] - mean * ga;
        gtab[256 + tid] = q_b[tid];
    }
#pragma unroll
    for (int r = 0; r < 16; r++) {
        int idx = tid + r * 256;            // 4096 float4 = 128 rows x 32
        int row = idx >> 5, c4 = idx & 31;
        float4 v = ((const float4*)q_w)[idx];
        unsigned int lo = (unsigned int)f2bf(v.x) | ((unsigned int)f2bf(v.y) << 16);
        unsigned int h2 = (unsigned int)f2bf(v.z) | ((unsigned int)f2bf(v.w) << 16);
        *(uint2*)&qw[row * 136 + c4 * 4] = make_uint2(lo, h2);
    }
    __syncthreads();

    // ---- prologue part 2: hn B-fragments (GN fused, coalesced half-wave) ----
    sv8 hn[8];
    {
        const float* xp = x + (size_t)b * kC * kHW + n0 + wave * 32 + lrow;
#pragma unroll
        for (int kc = 0; kc < 8; kc++) {
            int cb = kc * 16 + hi * 8;
            sv8 a;
#pragma unroll
            for (int j = 0; j < 8; j++) {
                float ga = gtab[cb + j], be = gtab[128 + cb + j];
                a[j] = (short)f2bf(xp[(size_t)(cb + j) * kHW] * ga + be);
            }
            hn[kc] = a;
        }
    }
    // ---- prologue part 3: Dq[o][n] = mfma(A=q_w, B=hn) ----
    f32x16 dq[4];
#pragma unroll
    for (int ot = 0; ot < 4; ot++)
#pragma unroll
        for (int r = 0; r < 16; r++) dq[ot][r] = 0.f;
#pragma unroll
    for (int ot = 0; ot < 4; ot++) {
        const unsigned short* arow = qw + (ot * 32 + lrow) * 136 + hi * 8;
#pragma unroll
        for (int kc = 0; kc < 8; kc++)
            dq[ot] = __builtin_amdgcn_mfma_f32_32x32x16_bf16(
                         *(const sv8*)(arow + kc * 16), hn[kc], dq[ot], 0, 0, 0);
    }
    // ---- prologue part 4: qa fragments via pack2 + shfl_xor(32) ----
    sv8 qa[8];
#pragma unroll
    for (int ot = 0; ot < 4; ot++) {
        unsigned int pk[4], pk2[4];
#pragma unroll
        for (int g = 0; g < 4; g++) {
            int ob = ot * 32 + 8 * g + 4 * hi;
            float v0 = (dq[ot][4 * g + 0] + gtab[256 + ob + 0]) * kScale;
            float v1 = (dq[ot][4 * g + 1] + gtab[256 + ob + 1]) * kScale;
            float v2 = (dq[ot][4 * g + 2] + gtab[256 + ob + 2]) * kScale;
            float v3 = (dq[ot][4 * g + 3] + gtab[256 + ob + 3]) * kScale;
            pk[g]  = pack2(v0, v1);
            pk2[g] = pack2(v2, v3);
        }
#pragma unroll
        for (int kk = 0; kk < 2; kk++) {
            unsigned int a_lo = pk[kk * 2],  a_hi = pk[kk * 2 + 1];
            unsigned int b_lo = pk2[kk * 2], b_hi = pk2[kk * 2 + 1];
            unsigned int own_a = hi ? a_hi : a_lo;
            unsigned int own_b = hi ? b_hi : b_lo;
            unsigned int rcv_a = (unsigned int)__shfl_xor((int)(hi ? a_lo : a_hi), 32, 64);
            unsigned int rcv_b = (unsigned int)__shfl_xor((int)(hi ? b_lo : b_hi), 32, 64);
            iv4 w;
            w[0] = (int)(hi ? rcv_a : own_a);
            w[1] = (int)(hi ? rcv_b : own_b);
            w[2] = (int)(hi ? own_a : rcv_a);
            w[3] = (int)(hi ? own_b : rcv_b);
            qa[2 * ot + kk] = __builtin_bit_cast(sv8, w);
        }
    }
    __syncthreads();   // all qw reads done; kv staging may overwrite

    // ---- main loop (round-9 core) ----
    f32x16 oacc[4];
#pragma unroll
    for (int ct = 0; ct < 4; ct++)
#pragma unroll
        for (int r = 0; r < 16; r++) oacc[ct][r] = 0.f;
    float rsumv = 0.f;

    const unsigned short* kvB  = kvb  + (size_t)b * kL * kC;
    const unsigned short* kvtB = kvtb + (size_t)b * kC * kL;

#define STAGE_TILE(tt) do {                                                     \
        int l0s = (tt) << 5;                                                    \
        char* dA = smem + (((tt) & 1) * 8192);                                  \
        char* dT = smem + 16384 + (((tt) & 1) * 8192);                          \
        _Pragma("unroll")                                                       \
        for (int i = 0; i < 2; i++) {                                           \
            int l = i * 16 + wave * 4 + (lane >> 4);                            \
            int ch = lane & 15;                                                 \
            const unsigned short* gs =                                          \
                kvB + (size_t)(l0s + l) * kC + ((ch ^ (l & 15)) * 8);           \
            GLOAD_LDS16(gs, dA + (i * 256 + wave * 64) * 16);                   \
        }                                                                       \
        _Pragma("unroll")                                                       \
        for (int i = 0; i < 2; i++) {                                           \
            int c = i * 64 + wave * 16 + (lane >> 2);                           \
            int ch = lane & 3;                                                  \
            const unsigned short* gs =                                          \
                kvtB + (size_t)c * kL + l0s + ((ch ^ ((c >> 1) & 3)) * 8);      \
            GLOAD_LDS16(gs, dT + (i * 256 + wave * 64) * 16);                   \
        }                                                                       \
    } while (0)

    STAGE_TILE(0);
    __syncthreads();           // barrier drains vmcnt -> tile 0 visible

    for (int t = 0; t < 16; t++) {
        const char* bufA = smem + (t & 1) * 8192;
        const char* bufT = smem + 16384 + (t & 1) * 8192;
        if (t < 15) STAGE_TILE(t + 1);    // in flight across the compute phase

        // ---- swapped QK^T: S[l][n] = mfma(A=kv, B=q); exp in registers ----
        f32x16 s;
#pragma unroll
        for (int r = 0; r < 16; r++) s[r] = 0.f;
        {
            const char* arow = bufA + lrow * 256;
            __builtin_amdgcn_s_setprio(1);
#pragma unroll
            for (int kc = 0; kc < 8; kc++)
                s = __builtin_amdgcn_mfma_f32_32x32x16_bf16(
                        *(const sv8*)(arow + ((kc * 32 + hi * 16) ^ swzA)),
                        qa[kc], s, 0, 0, 0);
            __builtin_amdgcn_s_setprio(0);
        }
        float p[16];
#pragma unroll
        for (int r = 0; r < 16; r++) {
            p[r] = __expf(s[r]);              // max-free: |logit| << 1
            rsumv += p[r];
        }
        unsigned int pk[4], pk2[4];
#pragma unroll
        for (int g = 0; g < 4; g++) {
            pk[g]  = pack2(p[4 * g + 0], p[4 * g + 1]);
            pk2[g] = pack2(p[4 * g + 2], p[4 * g + 3]);
        }
        // ---- assemble PV A-fragments ----
        sv8 pv[2];
#pragma unroll
        for (int kk = 0; kk < 2; kk++) {
            unsigned int a_lo = pk[kk * 2],  a_hi = pk[kk * 2 + 1];
            unsigned int b_lo = pk2[kk * 2], b_hi = pk2[kk * 2 + 1];
            unsigned int own_a = hi ? a_hi : a_lo;
            unsigned int own_b = hi ? b_hi : b_lo;
            unsigned int rcv_a = (unsigned int)__shfl_xor((int)(hi ? a_lo : a_hi), 32, 64);
            unsigned int rcv_b = (unsigned int)__shfl_xor((int)(hi ? b_lo : b_hi), 32, 64);
            iv4 w;
            w[0] = (int)(hi ? rcv_a : own_a);
            w[1] = (int)(hi ? rcv_b : own_b);
            w[2] = (int)(hi ? own_a : rcv_a);
            w[3] = (int)(hi ? own_b : rcv_b);
            pv[kk] = __builtin_bit_cast(sv8, w);
        }
        // ---- PV: O[n][c] += P[n][l] * kv[l][c]; B from swizzled kvT ----
        __builtin_amdgcn_s_setprio(1);
#pragma unroll
        for (int ct = 0; ct < 4; ct++) {
            const char* rowp = bufT + (ct * 32 + lrow) * 64;
#pragma unroll
            for (int kk = 0; kk < 2; kk++)
                oacc[ct] = __builtin_amdgcn_mfma_f32_32x32x16_bf16(
                               pv[kk],
                               *(const sv8*)(rowp + ((kk * 32 + hi * 16) ^ swzT)),
                               oacc[ct], 0, 0, 0);
        }
        __builtin_amdgcn_s_setprio(0);

        __syncthreads();   // drains vmcnt (t+1 landed) + guards dbuf swap
    }

    // ---- softmax denominators ----
    float total = rsumv + __shfl_xor(rsumv, 32, 64);
    float* rs = (float*)(smem + 36352) + wave * 32;
    rs[lrow] = 1.0f / total;                 // both halves write same value
    float rinv[16];
#pragma unroll
    for (int r = 0; r < 16; r++)
        rinv[r] = rs[(r & 3) + 8 * (r >> 2) + 4 * hi];

    unsigned short* o_lds = (unsigned short*)smem;   // [128][136]
    __syncthreads();
    // normalized O -> o_lds bf16 [128 n][136 c]  (per-wave row-disjoint)
#pragma unroll
    for (int ct = 0; ct < 4; ct++)
#pragma unroll
        for (int r = 0; r < 16; r++) {
            int n = wave * 32 + (r & 3) + 8 * (r >> 2) + 4 * hi;
            o_lds[n * 136 + ct * 32 + lrow] = f2bf(oacc[ct][r] * rinv[r]);
        }
    // proj: D[n][o] = O[n][c] * pw[o][c]
    sv8 oa[8];
    {
        const unsigned short* orow = o_lds + (wave * 32 + lrow) * 136 + hi * 8;
#pragma unroll
        for (int kc = 0; kc < 8; kc++) oa[kc] = *(const sv8*)(orow + kc * 16);
    }
    f32x16 dacc[4];
#pragma unroll
    for (int ot = 0; ot < 4; ot++)
#pragma unroll
        for (int r = 0; r < 16; r++) dacc[ot][r] = 0.f;
#pragma unroll
    for (int ot = 0; ot < 4; ot++) {
        const unsigned short* brow = pwb + (ot * 32 + lrow) * kC + hi * 8;
#pragma unroll
        for (int kc = 0; kc < 8; kc++)
            dacc[ot] = __builtin_amdgcn_mfma_f32_32x32x16_bf16(
                           oa[kc], *(const sv8*)(brow + kc * 16), dacc[ot], 0, 0, 0);
    }
    // D -> o_lds bf16 [128 n][136 o] (own rows only; reads already in regs)
#pragma unroll
    for (int ot = 0; ot < 4; ot++)
#pragma unroll
        for (int r = 0; r < 16; r++) {
            int n = wave * 32 + (r & 3) + 8 * (r >> 2) + 4 * hi;
            o_lds[n * 136 + ot * 32 + lrow] = f2bf(dacc[ot][r]);
        }
    __syncthreads();
    // epilogue: out[b][o][n0+n] = D[n][o] + proj_b[o] + x  (coalesced)
#pragma unroll 4
    for (int it = 0; it < 64; it++) {
        int idx = it * 256 + tid;
        int o = idx >> 7, n = idx & 127;
        size_t gi = ((size_t)b * kC + o) * kHW + n0 + n;
        out[gi] = bf2f(o_lds[n * 136 + o]) + proj_b[o] + x[gi];
    }
#undef STAGE_TILE
}

extern "C" void kernel_launch(void* const* d_in, const int* in_sizes, int n_in,
                              void* d_out, int out_size, void* d_ws, size_t ws_size,
                              hipStream_t stream) {
    const float* x      = (const float*)d_in[0];
    const float* nd     = (const float*)d_in[1];
    const float* gamma  = (const float*)d_in[2];
    const float* beta   = (const float*)d_in[3];
    const float* q_w    = (const float*)d_in[4];
    const float* q_b    = (const float*)d_in[5];
    const float* nd_w   = (const float*)d_in[6];
    const float* nd_b   = (const float*)d_in[7];
    const float* proj_w = (const float*)d_in[8];
    const float* proj_b = (const float*)d_in[9];
    float* out = (float*)d_out;

    float* stats           = (float*)d_ws;                  // 1024 f32
    unsigned short* pwb    = (unsigned short*)(stats + 1024);       // 16384
    unsigned short* kv_bf  = pwb + 16384;                   // 1,048,576
    unsigned short* kvT_bf = kv_bf + (size_t)kB * kL * kC;  // 1,048,576

    prep_all_k<<<dim3(1552), dim3(256), 0, stream>>>(
        x, nd, nd_w, nd_b, proj_w, stats, kv_bf, kvT_bf, pwb);
    attn_k<<<dim3(kHW / 128, kB), dim3(256), 0, stream>>>(
        x, stats, gamma, beta, q_w, q_b, kv_bf, kvT_bf, pwb, proj_b, out);
}

// Round 12
// 80.617 us; speedup vs baseline: 1.4162x; 1.0067x over previous
//
#include <hip/hip_runtime.h>
#include <math.h>

constexpr int kB = 16, kC = 128, kHW = 4096, kL = 512, kND = 256, kG = 32;
constexpr float kEps = 1e-6f;
constexpr float kScale = 0.08838834764831845f;  // 128^-0.5

typedef short sv8 __attribute__((ext_vector_type(8)));
typedef int   iv4 __attribute__((ext_vector_type(4)));
typedef float f32x16 __attribute__((ext_vector_type(16)));

static __device__ __forceinline__ unsigned short f2bf(float f) {
    unsigned int u = __builtin_bit_cast(unsigned int, f);
    u += 0x7fffu + ((u >> 16) & 1u);
    return (unsigned short)(u >> 16);
}
static __device__ __forceinline__ float bf2f(unsigned short s) {
    unsigned int u = ((unsigned int)s) << 16;
    return __builtin_bit_cast(float, u);
}
static __device__ __forceinline__ unsigned int pack2(float a, float b) {
    return (unsigned int)f2bf(a) | ((unsigned int)f2bf(b) << 16);
}

// Direct global->LDS async copy, 16 B/lane. LDS dest is wave-uniform base +
// lane*16 (linear); swizzle is applied by permuting the per-lane SOURCE.
#define GLOAD_LDS16(gp, lp)                                                     \
    __builtin_amdgcn_global_load_lds(                                           \
        (const __attribute__((address_space(1))) void*)(gp),                    \
        (__attribute__((address_space(3))) void*)(lp), 16, 0, 0)

// =========== Kernel 1: gn_stats + kv (+bf16/bf16^T) + proj_w->bf16 ==========
__global__ __launch_bounds__(256) void prep_all_k(
    const float* __restrict__ x, const float* __restrict__ nd,
    const float* __restrict__ nd_w, const float* __restrict__ nd_b,
    const float* __restrict__ proj_w,
    float* __restrict__ stats, unsigned short* __restrict__ kv_bf,
    unsigned short* __restrict__ kvT_bf, unsigned short* __restrict__ pwb)
{
    __shared__ float s_lds[8][256];
    __shared__ float w_lds[128][68];
    __shared__ float t_lds[8][129];
    __shared__ float red8[8];
    const int bid = blockIdx.x;
    const int tid = threadIdx.x;

    if (bid < 512) {
        // ---------------- GroupNorm statistics ----------------
        const float4* p4 = (const float4*)(x + (size_t)bid * 4 * kHW);
        float s = 0.f, ss = 0.f;
        for (int i = tid; i < 4096; i += 256) {
            float4 v = p4[i];
            s  += (v.x + v.y) + (v.z + v.w);
            ss += (v.x * v.x + v.y * v.y) + (v.z * v.z + v.w * v.w);
        }
#pragma unroll
        for (int off = 1; off < 64; off <<= 1) {
            s  += __shfl_xor(s, off, 64);
            ss += __shfl_xor(ss, off, 64);
        }
        int wid = tid >> 6;
        if ((tid & 63) == 0) { red8[wid] = s; red8[wid + 4] = ss; }
        __syncthreads();
        if (tid == 0) {
            float S  = (red8[0] + red8[1]) + (red8[2] + red8[3]);
            float SS = (red8[4] + red8[5]) + (red8[6] + red8[7]);
            float mean = S * (1.f / 16384.f);
            float var  = SS * (1.f / 16384.f) - mean * mean;
            stats[bid * 2]     = mean;
            stats[bid * 2 + 1] = rsqrtf(var + kEps);
        }
        return;
    }
    if (bid >= 1536) {
        // ---------------- proj_w -> bf16 ----------------
        int i = ((bid - 1536) * 256 + tid) * 4;
        float4 v = *(const float4*)(proj_w + i);
        pwb[i + 0] = f2bf(v.x); pwb[i + 1] = f2bf(v.y);
        pwb[i + 2] = f2bf(v.z); pwb[i + 3] = f2bf(v.w);
        return;
    }
    // ---------------- kv = silu(nd) @ nd_w^T + nd_b ----------------
    {
        int idx0 = bid - 512;
        int b = idx0 >> 6;
        int l0 = (idx0 & 63) * 8;
        const float4* ndp = (const float4*)(nd + ((size_t)b * kL + l0) * kND);
#pragma unroll
        for (int r = 0; r < 2; r++) {
            int idx = tid + r * 256;
            int row = idx >> 6;
            int c4 = idx & 63;
            float4 v = ndp[row * 64 + c4];
            v.x = v.x / (1.f + __expf(-v.x));
            v.y = v.y / (1.f + __expf(-v.y));
            v.z = v.z / (1.f + __expf(-v.z));
            v.w = v.w / (1.f + __expf(-v.w));
            *(float4*)&s_lds[row][c4 * 4] = v;
        }
        float acc[4] = {0.f, 0.f, 0.f, 0.f};
        int lr = tid >> 5;
        int oq = tid & 31;
        for (int d0 = 0; d0 < kND; d0 += 64) {
            __syncthreads();
#pragma unroll
            for (int r = 0; r < 8; r++) {
                int idx = tid + r * 256;
                int row = idx >> 4;
                int c4 = idx & 15;
                float4 v = ((const float4*)(nd_w + (size_t)row * kND + d0))[c4];
                *(float4*)&w_lds[row][c4 * 4] = v;
            }
            __syncthreads();
            for (int dd = 0; dd < 64; dd += 4) {
                float4 sv = *(const float4*)&s_lds[lr][d0 + dd];
#pragma unroll
                for (int j = 0; j < 4; j++) {
                    float4 wv = *(const float4*)&w_lds[oq + 32 * j][dd];
                    acc[j] += sv.x * wv.x + sv.y * wv.y + sv.z * wv.z + sv.w * wv.w;
                }
            }
        }
#pragma unroll
        for (int j = 0; j < 4; j++) {
            int o = oq + 32 * j;
            float vout = acc[j] + nd_b[o];
            kv_bf[((size_t)b * kL + l0 + lr) * kC + o] = f2bf(vout);
            t_lds[lr][o] = vout;
        }
        __syncthreads();
        int o = tid >> 1, lh = (tid & 1) * 4;
        unsigned long long pk = 0;
#pragma unroll
        for (int i = 0; i < 4; i++)
            pk |= (unsigned long long)f2bf(t_lds[lh + i][o]) << (16 * i);
        *(unsigned long long*)(kvT_bf + ((size_t)b * kC + o) * kL + l0 + lh) = pk;
    }
}

// ========== Kernel 2: fused GN+qproj prologue + attention + proj ============
// Disjoint-LDS prologue: kv tile-0 staging issued FIRST (latency hides under
// the whole prologue); x loaded into regs up front; q_w staged bf16 in two
// 64-row chunks (chunk-1 loads in flight during chunk-0 compute); gtab reads
// vectorized. Main loop = round-9 core (KVBLK=32, swapped QK^T, P in regs,
// global_load_lds with pre-swizzled sources, dbuf, 1 barrier/tile).
__global__ __launch_bounds__(256, 2) void attn_k(
    const float* __restrict__ x,
    const float* __restrict__ stats,
    const float* __restrict__ gamma,
    const float* __restrict__ beta,
    const float* __restrict__ q_w,
    const float* __restrict__ q_b,
    const unsigned short* __restrict__ kvb,   // [B][L][C] bf16
    const unsigned short* __restrict__ kvtb,  // [B][C][L] bf16
    const unsigned short* __restrict__ pwb,   // [C][C] bf16 (o-major)
    const float* __restrict__ proj_b,
    float* __restrict__ out)
{
    __shared__ __align__(16) char smem[52224];
    // [0,8192)+[8192,16384):      kvA dbuf ([32 l][128 c], ch16 ^= (l&15))
    // [16384,24576)+[24576,32768): kvT dbuf ([128 c][32 l], ch4 ^= ((c>>1)&3))
    // [32768,50176):  qw chunk [64][136] bf16 (prologue only)
    // [50176,51712):  gtab = ga[128] | be[128] | qb[128] f32
    // [51712,52224):  rs 4 waves x 32 f32
    // epilogue: o_lds ushort [128][136] at 0 (aliases kv+qw head; guarded)

    const int flat = blockIdx.y * gridDim.x + blockIdx.x;   // 0..511
    const int b  = ((flat & 7) << 1) | ((flat >> 3) & 1);   // XCD-clustered
    const int n0 = (flat >> 4) * 128;
    const int tid = threadIdx.x;
    const int wave = tid >> 6;
    const int lane = tid & 63;
    const int lrow = lane & 31;
    const int hi = lane >> 5;
    const int swzA = (lrow & 15) << 4;
    const int swzT = ((lrow >> 1) & 3) << 4;

    unsigned short* qw = (unsigned short*)(smem + 32768);  // [64][136]
    float* gtab = (float*)(smem + 50176);                  // ga | be | qb

    const unsigned short* kvB  = kvb  + (size_t)b * kL * kC;
    const unsigned short* kvtB = kvtb + (size_t)b * kC * kL;

#define STAGE_TILE(tt) do {                                                     \
        int l0s = (tt) << 5;                                                    \
        char* dA = smem + (((tt) & 1) * 8192);                                  \
        char* dT = smem + 16384 + (((tt) & 1) * 8192);                          \
        _Pragma("unroll")                                                       \
        for (int i = 0; i < 2; i++) {                                           \
            int l = i * 16 + wave * 4 + (lane >> 4);                            \
            int ch = lane & 15;                                                 \
            const unsigned short* gs =                                          \
                kvB + (size_t)(l0s + l) * kC + ((ch ^ (l & 15)) * 8);           \
            GLOAD_LDS16(gs, dA + (i * 256 + wave * 64) * 16);                   \
        }                                                                       \
        _Pragma("unroll")                                                       \
        for (int i = 0; i < 2; i++) {                                           \
            int c = i * 64 + wave * 16 + (lane >> 2);                           \
            int ch = lane & 3;                                                  \
            const unsigned short* gs =                                          \
                kvtB + (size_t)c * kL + l0s + ((ch ^ ((c >> 1) & 3)) * 8);      \
            GLOAD_LDS16(gs, dT + (i * 256 + wave * 64) * 16);                   \
        }                                                                       \
    } while (0)

    // ---- prologue: kv tile 0 staging FIRST (hides under everything) ----
    STAGE_TILE(0);

    if (tid < 128) {
        float mean = stats[(b * kG + (tid >> 2)) * 2];
        float rstd = stats[(b * kG + (tid >> 2)) * 2 + 1];
        float ga = gamma[tid] * rstd;
        gtab[tid] = ga;
        gtab[128 + tid] = beta[tid] - mean * ga;
        gtab[256 + tid] = q_b[tid];
    }
    // x slice into registers (64 independent loads, coalesced per half-wave)
    float xv[64];
    {
        const float* xp = x + (size_t)b * kC * kHW + n0 + wave * 32 + lrow;
#pragma unroll
        for (int c = 0; c < 64; c++) {
            int ch = (c >> 3) * 16 + hi * 8 + (c & 7);
            xv[c] = xp[(size_t)ch * kHW];
        }
    }
    // q_w chunk 0 (rows 0..63) -> LDS bf16
#pragma unroll
    for (int r = 0; r < 8; r++) {
        int idx = tid + r * 256;            // 2048 float4 = 64 rows x 32
        int row = idx >> 5, c4 = idx & 31;
        float4 v = ((const float4*)q_w)[row * 32 + c4];
        unsigned int lo = (unsigned int)f2bf(v.x) | ((unsigned int)f2bf(v.y) << 16);
        unsigned int h2 = (unsigned int)f2bf(v.z) | ((unsigned int)f2bf(v.w) << 16);
        *(uint2*)&qw[row * 136 + c4 * 4] = make_uint2(lo, h2);
    }
    __syncthreads();   // gtab + qw chunk0 visible; kv tile 0 landed (vmcnt)

    // q_w chunk 1 loads issued now (in flight across chunk-0 compute)
    float4 cv[8];
#pragma unroll
    for (int r = 0; r < 8; r++) {
        int idx = tid + r * 256;
        int row = idx >> 5, c4 = idx & 31;
        cv[r] = ((const float4*)q_w)[(64 + row) * 32 + c4];
    }
    // hn fragments (GN fused, vectorized table reads)
    sv8 hn[8];
#pragma unroll
    for (int kc = 0; kc < 8; kc++) {
        int cb = kc * 16 + hi * 8;
        float4 g0 = *(const float4*)&gtab[cb];
        float4 g1 = *(const float4*)&gtab[cb + 4];
        float4 e0 = *(const float4*)&gtab[128 + cb];
        float4 e1 = *(const float4*)&gtab[128 + cb + 4];
        sv8 a;
        a[0] = (short)f2bf(xv[kc * 8 + 0] * g0.x + e0.x);
        a[1] = (short)f2bf(xv[kc * 8 + 1] * g0.y + e0.y);
        a[2] = (short)f2bf(xv[kc * 8 + 2] * g0.z + e0.z);
        a[3] = (short)f2bf(xv[kc * 8 + 3] * g0.w + e0.w);
        a[4] = (short)f2bf(xv[kc * 8 + 4] * g1.x + e1.x);
        a[5] = (short)f2bf(xv[kc * 8 + 5] * g1.y + e1.y);
        a[6] = (short)f2bf(xv[kc * 8 + 6] * g1.z + e1.z);
        a[7] = (short)f2bf(xv[kc * 8 + 7] * g1.w + e1.w);
        hn[kc] = a;
    }
    // Dq[o][n] = mfma(A=q_w, B=hn) — chunk 0 (ot 0,1)
    f32x16 dq[4];
#pragma unroll
    for (int ot = 0; ot < 4; ot++)
#pragma unroll
        for (int r = 0; r < 16; r++) dq[ot][r] = 0.f;
#pragma unroll
    for (int ot = 0; ot < 2; ot++) {
        const unsigned short* arow = qw + (ot * 32 + lrow) * 136 + hi * 8;
#pragma unroll
        for (int kc = 0; kc < 8; kc++)
            dq[ot] = __builtin_amdgcn_mfma_f32_32x32x16_bf16(
                         *(const sv8*)(arow + kc * 16), hn[kc], dq[ot], 0, 0, 0);
    }
    __syncthreads();   // chunk-0 reads done
    // commit chunk 1 (rows 64..127 at local 0..63)
#pragma unroll
    for (int r = 0; r < 8; r++) {
        int idx = tid + r * 256;
        int row = idx >> 5, c4 = idx & 31;
        float4 v = cv[r];
        unsigned int lo = (unsigned int)f2bf(v.x) | ((unsigned int)f2bf(v.y) << 16);
        unsigned int h2 = (unsigned int)f2bf(v.z) | ((unsigned int)f2bf(v.w) << 16);
        *(uint2*)&qw[row * 136 + c4 * 4] = make_uint2(lo, h2);
    }
    __syncthreads();
#pragma unroll
    for (int ot = 2; ot < 4; ot++) {
        const unsigned short* arow = qw + ((ot - 2) * 32 + lrow) * 136 + hi * 8;
#pragma unroll
        for (int kc = 0; kc < 8; kc++)
            dq[ot] = __builtin_amdgcn_mfma_f32_32x32x16_bf16(
                         *(const sv8*)(arow + kc * 16), hn[kc], dq[ot], 0, 0, 0);
    }
    // qa fragments via pack2 + shfl_xor(32)
    sv8 qa[8];
#pragma unroll
    for (int ot = 0; ot < 4; ot++) {
        unsigned int pk[4], pk2[4];
#pragma unroll
        for (int g = 0; g < 4; g++) {
            int ob = ot * 32 + 8 * g + 4 * hi;
            float v0 = (dq[ot][4 * g + 0] + gtab[256 + ob + 0]) * kScale;
            float v1 = (dq[ot][4 * g + 1] + gtab[256 + ob + 1]) * kScale;
            float v2 = (dq[ot][4 * g + 2] + gtab[256 + ob + 2]) * kScale;
            float v3 = (dq[ot][4 * g + 3] + gtab[256 + ob + 3]) * kScale;
            pk[g]  = pack2(v0, v1);
            pk2[g] = pack2(v2, v3);
        }
#pragma unroll
        for (int kk = 0; kk < 2; kk++) {
            unsigned int a_lo = pk[kk * 2],  a_hi = pk[kk * 2 + 1];
            unsigned int b_lo = pk2[kk * 2], b_hi = pk2[kk * 2 + 1];
            unsigned int own_a = hi ? a_hi : a_lo;
            unsigned int own_b = hi ? b_hi : b_lo;
            unsigned int rcv_a = (unsigned int)__shfl_xor((int)(hi ? a_lo : a_hi), 32, 64);
            unsigned int rcv_b = (unsigned int)__shfl_xor((int)(hi ? b_lo : b_hi), 32, 64);
            iv4 w;
            w[0] = (int)(hi ? rcv_a : own_a);
            w[1] = (int)(hi ? rcv_b : own_b);
            w[2] = (int)(hi ? own_a : rcv_a);
            w[3] = (int)(hi ? own_b : rcv_b);
            qa[2 * ot + kk] = __builtin_bit_cast(sv8, w);
        }
    }
    // no barrier needed: qw area is disjoint from kv buffers

    // ---- main loop (round-9 core) ----
    f32x16 oacc[4];
#pragma unroll
    for (int ct = 0; ct < 4; ct++)
#pragma unroll
        for (int r = 0; r < 16; r++) oacc[ct][r] = 0.f;
    float rsumv = 0.f;

    for (int t = 0; t < 16; t++) {
        const char* bufA = smem + (t & 1) * 8192;
        const char* bufT = smem + 16384 + (t & 1) * 8192;
        if (t < 15) STAGE_TILE(t + 1);    // in flight across the compute phase

        // ---- swapped QK^T: S[l][n] = mfma(A=kv, B=q); exp in registers ----
        f32x16 s;
#pragma unroll
        for (int r = 0; r < 16; r++) s[r] = 0.f;
        {
            const char* arow = bufA + lrow * 256;
            __builtin_amdgcn_s_setprio(1);
#pragma unroll
            for (int kc = 0; kc < 8; kc++)
                s = __builtin_amdgcn_mfma_f32_32x32x16_bf16(
                        *(const sv8*)(arow + ((kc * 32 + hi * 16) ^ swzA)),
                        qa[kc], s, 0, 0, 0);
            __builtin_amdgcn_s_setprio(0);
        }
        float p[16];
#pragma unroll
        for (int r = 0; r < 16; r++) {
            p[r] = __expf(s[r]);              // max-free: |logit| << 1
            rsumv += p[r];
        }
        unsigned int pk[4], pk2[4];
#pragma unroll
        for (int g = 0; g < 4; g++) {
            pk[g]  = pack2(p[4 * g + 0], p[4 * g + 1]);
            pk2[g] = pack2(p[4 * g + 2], p[4 * g + 3]);
        }
        // ---- assemble PV A-fragments ----
        sv8 pv[2];
#pragma unroll
        for (int kk = 0; kk < 2; kk++) {
            unsigned int a_lo = pk[kk * 2],  a_hi = pk[kk * 2 + 1];
            unsigned int b_lo = pk2[kk * 2], b_hi = pk2[kk * 2 + 1];
            unsigned int own_a = hi ? a_hi : a_lo;
            unsigned int own_b = hi ? b_hi : b_lo;
            unsigned int rcv_a = (unsigned int)__shfl_xor((int)(hi ? a_lo : a_hi), 32, 64);
            unsigned int rcv_b = (unsigned int)__shfl_xor((int)(hi ? b_lo : b_hi), 32, 64);
            iv4 w;
            w[0] = (int)(hi ? rcv_a : own_a);
            w[1] = (int)(hi ? rcv_b : own_b);
            w[2] = (int)(hi ? own_a : rcv_a);
            w[3] = (int)(hi ? own_b : rcv_b);
            pv[kk] = __builtin_bit_cast(sv8, w);
        }
        // ---- PV: O[n][c] += P[n][l] * kv[l][c]; B from swizzled kvT ----
        __builtin_amdgcn_s_setprio(1);
#pragma unroll
        for (int ct = 0; ct < 4; ct++) {
            const char* rowp = bufT + (ct * 32 + lrow) * 64;
#pragma unroll
            for (int kk = 0; kk < 2; kk++)
                oacc[ct] = __builtin_amdgcn_mfma_f32_32x32x16_bf16(
                               pv[kk],
                               *(const sv8*)(rowp + ((kk * 32 + hi * 16) ^ swzT)),
                               oacc[ct], 0, 0, 0);
        }
        __builtin_amdgcn_s_setprio(0);

        __syncthreads();   // drains vmcnt (t+1 landed) + guards dbuf swap
    }

    // ---- softmax denominators ----
    float total = rsumv + __shfl_xor(rsumv, 32, 64);
    float* rs = (float*)(smem + 51712) + wave * 32;
    rs[lrow] = 1.0f / total;                 // both halves write same value
    float rinv[16];
#pragma unroll
    for (int r = 0; r < 16; r++)
        rinv[r] = rs[(r & 3) + 8 * (r >> 2) + 4 * hi];

    unsigned short* o_lds = (unsigned short*)smem;   // [128][136]
    __syncthreads();
    // normalized O -> o_lds bf16 [128 n][136 c]  (per-wave row-disjoint)
#pragma unroll
    for (int ct = 0; ct < 4; ct++)
#pragma unroll
        for (int r = 0; r < 16; r++) {
            int n = wave * 32 + (r & 3) + 8 * (r >> 2) + 4 * hi;
            o_lds[n * 136 + ct * 32 + lrow] = f2bf(oacc[ct][r] * rinv[r]);
        }
    // proj: D[n][o] = O[n][c] * pw[o][c]
    sv8 oa[8];
    {
        const unsigned short* orow = o_lds + (wave * 32 + lrow) * 136 + hi * 8;
#pragma unroll
        for (int kc = 0; kc < 8; kc++) oa[kc] = *(const sv8*)(orow + kc * 16);
    }
    f32x16 dacc[4];
#pragma unroll
    for (int ot = 0; ot < 4; ot++)
#pragma unroll
        for (int r = 0; r < 16; r++) dacc[ot][r] = 0.f;
#pragma unroll
    for (int ot = 0; ot < 4; ot++) {
        const unsigned short* brow = pwb + (ot * 32 + lrow) * kC + hi * 8;
#pragma unroll
        for (int kc = 0; kc < 8; kc++)
            dacc[ot] = __builtin_amdgcn_mfma_f32_32x32x16_bf16(
                           oa[kc], *(const sv8*)(brow + kc * 16), dacc[ot], 0, 0, 0);
    }
    // D -> o_lds bf16 [128 n][136 o] (own rows only; reads already in regs)
#pragma unroll
    for (int ot = 0; ot < 4; ot++)
#pragma unroll
        for (int r = 0; r < 16; r++) {
            int n = wave * 32 + (r & 3) + 8 * (r >> 2) + 4 * hi;
            o_lds[n * 136 + ot * 32 + lrow] = f2bf(dacc[ot][r]);
        }
    __syncthreads();
    // epilogue: out[b][o][n0+n] = D[n][o] + proj_b[o] + x  (coalesced)
#pragma unroll 4
    for (int it = 0; it < 64; it++) {
        int idx = it * 256 + tid;
        int o = idx >> 7, n = idx & 127;
        size_t gi = ((size_t)b * kC + o) * kHW + n0 + n;
        out[gi] = bf2f(o_lds[n * 136 + o]) + proj_b[o] + x[gi];
    }
#undef STAGE_TILE
}

extern "C" void kernel_launch(void* const* d_in, const int* in_sizes, int n_in,
                              void* d_out, int out_size, void* d_ws, size_t ws_size,
                              hipStream_t stream) {
    const float* x      = (const float*)d_in[0];
    const float* nd     = (const float*)d_in[1];
    const float* gamma  = (const float*)d_in[2];
    const float* beta   = (const float*)d_in[3];
    const float* q_w    = (const float*)d_in[4];
    const float* q_b    = (const float*)d_in[5];
    const float* nd_w   = (const float*)d_in[6];
    const float* nd_b   = (const float*)d_in[7];
    const float* proj_w = (const float*)d_in[8];
    const float* proj_b = (const float*)d_in[9];
    float* out = (float*)d_out;

    float* stats           = (float*)d_ws;                  // 1024 f32
    unsigned short* pwb    = (unsigned short*)(stats + 1024);       // 16384
    unsigned short* kv_bf  = pwb + 16384;                   // 1,048,576
    unsigned short* kvT_bf = kv_bf + (size_t)kB * kL * kC;  // 1,048,576

    prep_all_k<<<dim3(1552), dim3(256), 0, stream>>>(
        x, nd, nd_w, nd_b, proj_w, stats, kv_bf, kvT_bf, pwb);
    attn_k<<<dim3(kHW / 128, kB), dim3(256), 0, stream>>>(
        x, stats, gamma, beta, q_w, q_b, kv_bf, kvT_bf, pwb, proj_b, out);
}

// Round 13
// 80.494 us; speedup vs baseline: 1.4184x; 1.0015x over previous
//
#include <hip/hip_runtime.h>
#include <math.h>

constexpr int kB = 16, kC = 128, kHW = 4096, kL = 512, kND = 256, kG = 32;
constexpr float kEps = 1e-6f;
constexpr float kScale = 0.08838834764831845f;  // 128^-0.5

typedef short sv8 __attribute__((ext_vector_type(8)));
typedef int   iv4 __attribute__((ext_vector_type(4)));
typedef float f32x16 __attribute__((ext_vector_type(16)));

static __device__ __forceinline__ unsigned short f2bf(float f) {
    unsigned int u = __builtin_bit_cast(unsigned int, f);
    u += 0x7fffu + ((u >> 16) & 1u);
    return (unsigned short)(u >> 16);
}
static __device__ __forceinline__ float bf2f(unsigned short s) {
    unsigned int u = ((unsigned int)s) << 16;
    return __builtin_bit_cast(float, u);
}
static __device__ __forceinline__ unsigned int pack2(float a, float b) {
    return (unsigned int)f2bf(a) | ((unsigned int)f2bf(b) << 16);
}

// Direct global->LDS async copy, 16 B/lane. LDS dest is wave-uniform base +
// lane*16 (linear); swizzle is applied by permuting the per-lane SOURCE.
#define GLOAD_LDS16(gp, lp)                                                     \
    __builtin_amdgcn_global_load_lds(                                           \
        (const __attribute__((address_space(1))) void*)(gp),                    \
        (__attribute__((address_space(3))) void*)(lp), 16, 0, 0)

// =========== Kernel 1: gn_stats + kv (+bf16/bf16^T) + proj_w->bf16 ==========
__global__ __launch_bounds__(256) void prep_all_k(
    const float* __restrict__ x, const float* __restrict__ nd,
    const float* __restrict__ nd_w, const float* __restrict__ nd_b,
    const float* __restrict__ proj_w,
    float* __restrict__ stats, unsigned short* __restrict__ kv_bf,
    unsigned short* __restrict__ kvT_bf, unsigned short* __restrict__ pwb)
{
    __shared__ float s_lds[8][256];
    __shared__ float w_lds[128][68];
    __shared__ float t_lds[8][129];
    __shared__ float red8[8];
    const int bid = blockIdx.x;
    const int tid = threadIdx.x;

    if (bid < 512) {
        // ---------------- GroupNorm statistics ----------------
        const float4* p4 = (const float4*)(x + (size_t)bid * 4 * kHW);
        float s = 0.f, ss = 0.f;
        for (int i = tid; i < 4096; i += 256) {
            float4 v = p4[i];
            s  += (v.x + v.y) + (v.z + v.w);
            ss += (v.x * v.x + v.y * v.y) + (v.z * v.z + v.w * v.w);
        }
#pragma unroll
        for (int off = 1; off < 64; off <<= 1) {
            s  += __shfl_xor(s, off, 64);
            ss += __shfl_xor(ss, off, 64);
        }
        int wid = tid >> 6;
        if ((tid & 63) == 0) { red8[wid] = s; red8[wid + 4] = ss; }
        __syncthreads();
        if (tid == 0) {
            float S  = (red8[0] + red8[1]) + (red8[2] + red8[3]);
            float SS = (red8[4] + red8[5]) + (red8[6] + red8[7]);
            float mean = S * (1.f / 16384.f);
            float var  = SS * (1.f / 16384.f) - mean * mean;
            stats[bid * 2]     = mean;
            stats[bid * 2 + 1] = rsqrtf(var + kEps);
        }
        return;
    }
    if (bid >= 1536) {
        // ---------------- proj_w -> bf16 ----------------
        int i = ((bid - 1536) * 256 + tid) * 4;
        float4 v = *(const float4*)(proj_w + i);
        pwb[i + 0] = f2bf(v.x); pwb[i + 1] = f2bf(v.y);
        pwb[i + 2] = f2bf(v.z); pwb[i + 3] = f2bf(v.w);
        return;
    }
    // ---------------- kv = silu(nd) @ nd_w^T + nd_b ----------------
    {
        int idx0 = bid - 512;
        int b = idx0 >> 6;
        int l0 = (idx0 & 63) * 8;
        const float4* ndp = (const float4*)(nd + ((size_t)b * kL + l0) * kND);
#pragma unroll
        for (int r = 0; r < 2; r++) {
            int idx = tid + r * 256;
            int row = idx >> 6;
            int c4 = idx & 63;
            float4 v = ndp[row * 64 + c4];
            v.x = v.x / (1.f + __expf(-v.x));
            v.y = v.y / (1.f + __expf(-v.y));
            v.z = v.z / (1.f + __expf(-v.z));
            v.w = v.w / (1.f + __expf(-v.w));
            *(float4*)&s_lds[row][c4 * 4] = v;
        }
        float acc[4] = {0.f, 0.f, 0.f, 0.f};
        int lr = tid >> 5;
        int oq = tid & 31;
        for (int d0 = 0; d0 < kND; d0 += 64) {
            __syncthreads();
#pragma unroll
            for (int r = 0; r < 8; r++) {
                int idx = tid + r * 256;
                int row = idx >> 4;
                int c4 = idx & 15;
                float4 v = ((const float4*)(nd_w + (size_t)row * kND + d0))[c4];
                *(float4*)&w_lds[row][c4 * 4] = v;
            }
            __syncthreads();
            for (int dd = 0; dd < 64; dd += 4) {
                float4 sv = *(const float4*)&s_lds[lr][d0 + dd];
#pragma unroll
                for (int j = 0; j < 4; j++) {
                    float4 wv = *(const float4*)&w_lds[oq + 32 * j][dd];
                    acc[j] += sv.x * wv.x + sv.y * wv.y + sv.z * wv.z + sv.w * wv.w;
                }
            }
        }
#pragma unroll
        for (int j = 0; j < 4; j++) {
            int o = oq + 32 * j;
            float vout = acc[j] + nd_b[o];
            kv_bf[((size_t)b * kL + l0 + lr) * kC + o] = f2bf(vout);
            t_lds[lr][o] = vout;
        }
        __syncthreads();
        int o = tid >> 1, lh = (tid & 1) * 4;
        unsigned long long pk = 0;
#pragma unroll
        for (int i = 0; i < 4; i++)
            pk |= (unsigned long long)f2bf(t_lds[lh + i][o]) << (16 * i);
        *(unsigned long long*)(kvT_bf + ((size_t)b * kC + o) * kL + l0 + lh) = pk;
    }
}

// ========== Kernel 2: fused GN+qproj prologue + attention + proj ============
// amdgpu_waves_per_eu(2,2): grid pins us to 2 blocks/CU (2 waves/SIMD), so
// allow the full 256-VGPR budget — prevents the allocator from sinking /
// spilling the prologue's xv[64]/cv[8] load batches (rounds 11-12: VGPR=80,
// loads serialized at use sites). sched_barrier(0) pins the issue points.
__global__ __launch_bounds__(256) __attribute__((amdgpu_waves_per_eu(2, 2)))
void attn_k(
    const float* __restrict__ x,
    const float* __restrict__ stats,
    const float* __restrict__ gamma,
    const float* __restrict__ beta,
    const float* __restrict__ q_w,
    const float* __restrict__ q_b,
    const unsigned short* __restrict__ kvb,   // [B][L][C] bf16
    const unsigned short* __restrict__ kvtb,  // [B][C][L] bf16
    const unsigned short* __restrict__ pwb,   // [C][C] bf16 (o-major)
    const float* __restrict__ proj_b,
    float* __restrict__ out)
{
    __shared__ __align__(16) char smem[52224];
    // [0,8192)+[8192,16384):      kvA dbuf ([32 l][128 c], ch16 ^= (l&15))
    // [16384,24576)+[24576,32768): kvT dbuf ([128 c][32 l], ch4 ^= ((c>>1)&3))
    // [32768,50176):  qw chunk [64][136] bf16 (prologue only)
    // [50176,51712):  gtab = ga[128] | be[128] | qb[128] f32
    // [51712,52224):  rs 4 waves x 32 f32
    // epilogue: o_lds ushort [128][136] at 0 (aliases kv+qw head; guarded)

    const int flat = blockIdx.y * gridDim.x + blockIdx.x;   // 0..511
    const int b  = ((flat & 7) << 1) | ((flat >> 3) & 1);   // XCD-clustered
    const int n0 = (flat >> 4) * 128;
    const int tid = threadIdx.x;
    const int wave = tid >> 6;
    const int lane = tid & 63;
    const int lrow = lane & 31;
    const int hi = lane >> 5;
    const int swzA = (lrow & 15) << 4;
    const int swzT = ((lrow >> 1) & 3) << 4;

    unsigned short* qw = (unsigned short*)(smem + 32768);  // [64][136]
    float* gtab = (float*)(smem + 50176);                  // ga | be | qb

    const unsigned short* kvB  = kvb  + (size_t)b * kL * kC;
    const unsigned short* kvtB = kvtb + (size_t)b * kC * kL;

#define STAGE_TILE(tt) do {                                                     \
        int l0s = (tt) << 5;                                                    \
        char* dA = smem + (((tt) & 1) * 8192);                                  \
        char* dT = smem + 16384 + (((tt) & 1) * 8192);                          \
        _Pragma("unroll")                                                       \
        for (int i = 0; i < 2; i++) {                                           \
            int l = i * 16 + wave * 4 + (lane >> 4);                            \
            int ch = lane & 15;                                                 \
            const unsigned short* gs =                                          \
                kvB + (size_t)(l0s + l) * kC + ((ch ^ (l & 15)) * 8);           \
            GLOAD_LDS16(gs, dA + (i * 256 + wave * 64) * 16);                   \
        }                                                                       \
        _Pragma("unroll")                                                       \
        for (int i = 0; i < 2; i++) {                                           \
            int c = i * 64 + wave * 16 + (lane >> 2);                           \
            int ch = lane & 3;                                                  \
            const unsigned short* gs =                                          \
                kvtB + (size_t)c * kL + l0s + ((ch ^ ((c >> 1) & 3)) * 8);      \
            GLOAD_LDS16(gs, dT + (i * 256 + wave * 64) * 16);                   \
        }                                                                       \
    } while (0)

    // ---- prologue: kv tile 0 staging FIRST (hides under everything) ----
    STAGE_TILE(0);

    if (tid < 128) {
        float mean = stats[(b * kG + (tid >> 2)) * 2];
        float rstd = stats[(b * kG + (tid >> 2)) * 2 + 1];
        float ga = gamma[tid] * rstd;
        gtab[tid] = ga;
        gtab[128 + tid] = beta[tid] - mean * ga;
        gtab[256 + tid] = q_b[tid];
    }
    // x slice into registers (64 independent loads, coalesced per half-wave)
    float xv[64];
    {
        const float* xp = x + (size_t)b * kC * kHW + n0 + wave * 32 + lrow;
#pragma unroll
        for (int c = 0; c < 64; c++) {
            int ch = (c >> 3) * 16 + hi * 8 + (c & 7);
            xv[c] = xp[(size_t)ch * kHW];
        }
    }
    __builtin_amdgcn_sched_barrier(0);   // pin: do NOT sink xv loads
    // q_w chunk 0 (rows 0..63) -> LDS bf16
#pragma unroll
    for (int r = 0; r < 8; r++) {
        int idx = tid + r * 256;            // 2048 float4 = 64 rows x 32
        int row = idx >> 5, c4 = idx & 31;
        float4 v = ((const float4*)q_w)[row * 32 + c4];
        unsigned int lo = (unsigned int)f2bf(v.x) | ((unsigned int)f2bf(v.y) << 16);
        unsigned int h2 = (unsigned int)f2bf(v.z) | ((unsigned int)f2bf(v.w) << 16);
        *(uint2*)&qw[row * 136 + c4 * 4] = make_uint2(lo, h2);
    }
    __syncthreads();   // gtab + qw chunk0 visible; kv tile 0 landed (vmcnt)

    // q_w chunk 1 loads issued now (in flight across chunk-0 compute)
    float4 cv[8];
#pragma unroll
    for (int r = 0; r < 8; r++) {
        int idx = tid + r * 256;
        int row = idx >> 5, c4 = idx & 31;
        cv[r] = ((const float4*)q_w)[(64 + row) * 32 + c4];
    }
    __builtin_amdgcn_sched_barrier(0);   // pin: do NOT sink cv loads
    // hn fragments (GN fused, vectorized table reads)
    sv8 hn[8];
#pragma unroll
    for (int kc = 0; kc < 8; kc++) {
        int cb = kc * 16 + hi * 8;
        float4 g0 = *(const float4*)&gtab[cb];
        float4 g1 = *(const float4*)&gtab[cb + 4];
        float4 e0 = *(const float4*)&gtab[128 + cb];
        float4 e1 = *(const float4*)&gtab[128 + cb + 4];
        sv8 a;
        a[0] = (short)f2bf(xv[kc * 8 + 0] * g0.x + e0.x);
        a[1] = (short)f2bf(xv[kc * 8 + 1] * g0.y + e0.y);
        a[2] = (short)f2bf(xv[kc * 8 + 2] * g0.z + e0.z);
        a[3] = (short)f2bf(xv[kc * 8 + 3] * g0.w + e0.w);
        a[4] = (short)f2bf(xv[kc * 8 + 4] * g1.x + e1.x);
        a[5] = (short)f2bf(xv[kc * 8 + 5] * g1.y + e1.y);
        a[6] = (short)f2bf(xv[kc * 8 + 6] * g1.z + e1.z);
        a[7] = (short)f2bf(xv[kc * 8 + 7] * g1.w + e1.w);
        hn[kc] = a;
    }
    // Dq[o][n] = mfma(A=q_w, B=hn) — chunk 0 (ot 0,1)
    f32x16 dq[4];
#pragma unroll
    for (int ot = 0; ot < 4; ot++)
#pragma unroll
        for (int r = 0; r < 16; r++) dq[ot][r] = 0.f;
#pragma unroll
    for (int ot = 0; ot < 2; ot++) {
        const unsigned short* arow = qw + (ot * 32 + lrow) * 136 + hi * 8;
#pragma unroll
        for (int kc = 0; kc < 8; kc++)
            dq[ot] = __builtin_amdgcn_mfma_f32_32x32x16_bf16(
                         *(const sv8*)(arow + kc * 16), hn[kc], dq[ot], 0, 0, 0);
    }
    __syncthreads();   // chunk-0 reads done
    // commit chunk 1 (rows 64..127 at local 0..63)
#pragma unroll
    for (int r = 0; r < 8; r++) {
        int idx = tid + r * 256;
        int row = idx >> 5, c4 = idx & 31;
        float4 v = cv[r];
        unsigned int lo = (unsigned int)f2bf(v.x) | ((unsigned int)f2bf(v.y) << 16);
        unsigned int h2 = (unsigned int)f2bf(v.z) | ((unsigned int)f2bf(v.w) << 16);
        *(uint2*)&qw[row * 136 + c4 * 4] = make_uint2(lo, h2);
    }
    __syncthreads();
#pragma unroll
    for (int ot = 2; ot < 4; ot++) {
        const unsigned short* arow = qw + ((ot - 2) * 32 + lrow) * 136 + hi * 8;
#pragma unroll
        for (int kc = 0; kc < 8; kc++)
            dq[ot] = __builtin_amdgcn_mfma_f32_32x32x16_bf16(
                         *(const sv8*)(arow + kc * 16), hn[kc], dq[ot], 0, 0, 0);
    }
    // qa fragments via pack2 + shfl_xor(32)
    sv8 qa[8];
#pragma unroll
    for (int ot = 0; ot < 4; ot++) {
        unsigned int pk[4], pk2[4];
#pragma unroll
        for (int g = 0; g < 4; g++) {
            int ob = ot * 32 + 8 * g + 4 * hi;
            float v0 = (dq[ot][4 * g + 0] + gtab[256 + ob + 0]) * kScale;
            float v1 = (dq[ot][4 * g + 1] + gtab[256 + ob + 1]) * kScale;
            float v2 = (dq[ot][4 * g + 2] + gtab[256 + ob + 2]) * kScale;
            float v3 = (dq[ot][4 * g + 3] + gtab[256 + ob + 3]) * kScale;
            pk[g]  = pack2(v0, v1);
            pk2[g] = pack2(v2, v3);
        }
#pragma unroll
        for (int kk = 0; kk < 2; kk++) {
            unsigned int a_lo = pk[kk * 2],  a_hi = pk[kk * 2 + 1];
            unsigned int b_lo = pk2[kk * 2], b_hi = pk2[kk * 2 + 1];
            unsigned int own_a = hi ? a_hi : a_lo;
            unsigned int own_b = hi ? b_hi : b_lo;
            unsigned int rcv_a = (unsigned int)__shfl_xor((int)(hi ? a_lo : a_hi), 32, 64);
            unsigned int rcv_b = (unsigned int)__shfl_xor((int)(hi ? b_lo : b_hi), 32, 64);
            iv4 w;
            w[0] = (int)(hi ? rcv_a : own_a);
            w[1] = (int)(hi ? rcv_b : own_b);
            w[2] = (int)(hi ? own_a : rcv_a);
            w[3] = (int)(hi ? own_b : rcv_b);
            qa[2 * ot + kk] = __builtin_bit_cast(sv8, w);
        }
    }
    // no barrier needed: qw area is disjoint from kv buffers

    // ---- main loop (round-9 core) ----
    f32x16 oacc[4];
#pragma unroll
    for (int ct = 0; ct < 4; ct++)
#pragma unroll
        for (int r = 0; r < 16; r++) oacc[ct][r] = 0.f;
    float rsumv = 0.f;

    for (int t = 0; t < 16; t++) {
        const char* bufA = smem + (t & 1) * 8192;
        const char* bufT = smem + 16384 + (t & 1) * 8192;
        if (t < 15) STAGE_TILE(t + 1);    // in flight across the compute phase

        // ---- swapped QK^T: S[l][n] = mfma(A=kv, B=q); exp in registers ----
        f32x16 s;
#pragma unroll
        for (int r = 0; r < 16; r++) s[r] = 0.f;
        {
            const char* arow = bufA + lrow * 256;
            __builtin_amdgcn_s_setprio(1);
#pragma unroll
            for (int kc = 0; kc < 8; kc++)
                s = __builtin_amdgcn_mfma_f32_32x32x16_bf16(
                        *(const sv8*)(arow + ((kc * 32 + hi * 16) ^ swzA)),
                        qa[kc], s, 0, 0, 0);
            __builtin_amdgcn_s_setprio(0);
        }
        float p[16];
#pragma unroll
        for (int r = 0; r < 16; r++) {
            p[r] = __expf(s[r]);              // max-free: |logit| << 1
            rsumv += p[r];
        }
        unsigned int pk[4], pk2[4];
#pragma unroll
        for (int g = 0; g < 4; g++) {
            pk[g]  = pack2(p[4 * g + 0], p[4 * g + 1]);
            pk2[g] = pack2(p[4 * g + 2], p[4 * g + 3]);
        }
        // ---- assemble PV A-fragments ----
        sv8 pv[2];
#pragma unroll
        for (int kk = 0; kk < 2; kk++) {
            unsigned int a_lo = pk[kk * 2],  a_hi = pk[kk * 2 + 1];
            unsigned int b_lo = pk2[kk * 2], b_hi = pk2[kk * 2 + 1];
            unsigned int own_a = hi ? a_hi : a_lo;
            unsigned int own_b = hi ? b_hi : b_lo;
            unsigned int rcv_a = (unsigned int)__shfl_xor((int)(hi ? a_lo : a_hi), 32, 64);
            unsigned int rcv_b = (unsigned int)__shfl_xor((int)(hi ? b_lo : b_hi), 32, 64);
            iv4 w;
            w[0] = (int)(hi ? rcv_a : own_a);
            w[1] = (int)(hi ? rcv_b : own_b);
            w[2] = (int)(hi ? own_a : rcv_a);
            w[3] = (int)(hi ? own_b : rcv_b);
            pv[kk] = __builtin_bit_cast(sv8, w);
        }
        // ---- PV: O[n][c] += P[n][l] * kv[l][c]; B from swizzled kvT ----
        __builtin_amdgcn_s_setprio(1);
#pragma unroll
        for (int ct = 0; ct < 4; ct++) {
            const char* rowp = bufT + (ct * 32 + lrow) * 64;
#pragma unroll
            for (int kk = 0; kk < 2; kk++)
                oacc[ct] = __builtin_amdgcn_mfma_f32_32x32x16_bf16(
                               pv[kk],
                               *(const sv8*)(rowp + ((kk * 32 + hi * 16) ^ swzT)),
                               oacc[ct], 0, 0, 0);
        }
        __builtin_amdgcn_s_setprio(0);

        __syncthreads();   // drains vmcnt (t+1 landed) + guards dbuf swap
    }

    // ---- softmax denominators ----
    float total = rsumv + __shfl_xor(rsumv, 32, 64);
    float* rs = (float*)(smem + 51712) + wave * 32;
    rs[lrow] = 1.0f / total;                 // both halves write same value
    float rinv[16];
#pragma unroll
    for (int r = 0; r < 16; r++)
        rinv[r] = rs[(r & 3) + 8 * (r >> 2) + 4 * hi];

    unsigned short* o_lds = (unsigned short*)smem;   // [128][136]
    __syncthreads();
    // normalized O -> o_lds bf16 [128 n][136 c]  (per-wave row-disjoint)
#pragma unroll
    for (int ct = 0; ct < 4; ct++)
#pragma unroll
        for (int r = 0; r < 16; r++) {
            int n = wave * 32 + (r & 3) + 8 * (r >> 2) + 4 * hi;
            o_lds[n * 136 + ct * 32 + lrow] = f2bf(oacc[ct][r] * rinv[r]);
        }
    // proj: D[n][o] = O[n][c] * pw[o][c]
    sv8 oa[8];
    {
        const unsigned short* orow = o_lds + (wave * 32 + lrow) * 136 + hi * 8;
#pragma unroll
        for (int kc = 0; kc < 8; kc++) oa[kc] = *(const sv8*)(orow + kc * 16);
    }
    f32x16 dacc[4];
#pragma unroll
    for (int ot = 0; ot < 4; ot++)
#pragma unroll
        for (int r = 0; r < 16; r++) dacc[ot][r] = 0.f;
#pragma unroll
    for (int ot = 0; ot < 4; ot++) {
        const unsigned short* brow = pwb + (ot * 32 + lrow) * kC + hi * 8;
#pragma unroll
        for (int kc = 0; kc < 8; kc++)
            dacc[ot] = __builtin_amdgcn_mfma_f32_32x32x16_bf16(
                           oa[kc], *(const sv8*)(brow + kc * 16), dacc[ot], 0, 0, 0);
    }
    // D -> o_lds bf16 [128 n][136 o] (own rows only; reads already in regs)
#pragma unroll
    for (int ot = 0; ot < 4; ot++)
#pragma unroll
        for (int r = 0; r < 16; r++) {
            int n = wave * 32 + (r & 3) + 8 * (r >> 2) + 4 * hi;
            o_lds[n * 136 + ot * 32 + lrow] = f2bf(dacc[ot][r]);
        }
    __syncthreads();
    // epilogue: out[b][o][n0+n] = D[n][o] + proj_b[o] + x  (coalesced)
#pragma unroll 4
    for (int it = 0; it < 64; it++) {
        int idx = it * 256 + tid;
        int o = idx >> 7, n = idx & 127;
        size_t gi = ((size_t)b * kC + o) * kHW + n0 + n;
        out[gi] = bf2f(o_lds[n * 136 + o]) + proj_b[o] + x[gi];
    }
#undef STAGE_TILE
}

extern "C" void kernel_launch(void* const* d_in, const int* in_sizes, int n_in,
                              void* d_out, int out_size, void* d_ws, size_t ws_size,
                              hipStream_t stream) {
    const float* x      = (const float*)d_in[0];
    const float* nd     = (const float*)d_in[1];
    const float* gamma  = (const float*)d_in[2];
    const float* beta   = (const float*)d_in[3];
    const float* q_w    = (const float*)d_in[4];
    const float* q_b    = (const float*)d_in[5];
    const float* nd_w   = (const float*)d_in[6];
    const float* nd_b   = (const float*)d_in[7];
    const float* proj_w = (const float*)d_in[8];
    const float* proj_b = (const float*)d_in[9];
    float* out = (float*)d_out;

    float* stats           = (float*)d_ws;                  // 1024 f32
    unsigned short* pwb    = (unsigned short*)(stats + 1024);       // 16384
    unsigned short* kv_bf  = pwb + 16384;                   // 1,048,576
    unsigned short* kvT_bf = kv_bf + (size_t)kB * kL * kC;  // 1,048,576

    prep_all_k<<<dim3(1552), dim3(256), 0, stream>>>(
        x, nd, nd_w, nd_b, proj_w, stats, kv_bf, kvT_bf, pwb);
    attn_k<<<dim3(kHW / 128, kB), dim3(256), 0, stream>>>(
        x, stats, gamma, beta, q_w, q_b, kv_bf, kvT_bf, pwb, proj_b, out);
}